// Round 7
// baseline (521.417 us; speedup 1.0000x reference)
//
#include <hip/hip_runtime.h>

// ---------------------------------------------------------------------------
// BiMambaEncoderBlock on MI355X (gfx950). fp32 accumulate, bf16 intermediates.
// B=2, S=1024, D_MODEL=256, D_INNER=512, D_STATE=64, DT_RANK=16, D_CONV=4.
// Round 7: scan operands precomputed+transposed (dtT/dxT bf16 [dirb][d][t],
// BT/CT f32 [dirb][n][t]) -> 5 vector loads per 8-step window; 8 chunks of
// 128 (pass1 computes 7 summaries) -> ~full occupancy; ln2 fused into
// outproj epilogue. dtproj + ln2 kernels and xssm buffer removed.
// ---------------------------------------------------------------------------

typedef unsigned short u16;
typedef short bf16x8 __attribute__((ext_vector_type(8)));   // 8 bf16 = 4 VGPRs
typedef float f32x4  __attribute__((ext_vector_type(4)));

#define MFMA(a, b, c) __builtin_amdgcn_mfma_f32_16x16x32_bf16((a), (b), (c), 0, 0, 0)

static constexpr int ROWS = 2048;   // B*S
static constexpr int DM   = 256;    // d_model
static constexpr int DI   = 512;    // d_inner
static constexpr int NXZ  = 1024;   // 2*d_inner
static constexpr int NDBL = 144;    // dt_rank + 2*d_state
static constexpr int DS   = 64;     // d_state

__device__ __forceinline__ float bf2f(u16 u) {
  union { unsigned u32; float f; } v; v.u32 = ((unsigned)u) << 16; return v.f;
}
__device__ __forceinline__ u16 f2bf(float f) {
  union { float f; unsigned u; } v; v.f = f;
  unsigned r = v.u + 0x7FFFu + ((v.u >> 16) & 1u);   // RNE (finite inputs)
  return (u16)(r >> 16);
}
__device__ __forceinline__ float ldx(const void* p, size_t i, int f32) {
  return f32 ? ((const float*)p)[i] : bf2f(((const u16*)p)[i]);
}

// ---- workspace layout (bytes) ----
static constexpr size_t XN_OFF   = 0;          // bf16 [2048][256]
static constexpr size_t XZ_OFF   = 1048576;    // bf16 [2][2048][1024]
static constexpr size_t XC_OFF   = 9437184;    // bf16 [2][2048][512]  (row=dirb*1024+t)
static constexpr size_t DBL_OFF  = 13631488;   // f32  [4096][144]
static constexpr size_t DTT_OFF  = 15990784;   // bf16 [4][512][1024]  dt  (dirb,d,t)
static constexpr size_t DXT_OFF  = 20185088;   // bf16 [4][512][1024]  dt*xc
static constexpr size_t BT_OFF   = 24379392;   // f32  [4][64][1024]   B   (dirb,n,t)
static constexpr size_t CT_OFF   = 25427968;   // f32  [4][64][1024]   C
static constexpr size_t Y_OFF    = 26476544;   // bf16 [4096][512]
static constexpr size_t X2_OFF   = 30670848;   // bf16 [2048][256]
static constexpr size_t PCH_OFF  = 31719424;   // f32  [2048][7][64]
static constexpr size_t BCH_OFF  = 35389440;   // f32  [2048][7][64]
static constexpr size_t FLAG_OFF = 39059456;   // int
static constexpr size_t WB_OFF   = 39059472;   // bf16 weights
// converted-weight region (element offsets within WB):
static constexpr int WB_IWF = 0;        // f_in_w  [1024][256]
static constexpr int WB_IWB = 262144;   // b_in_w  [1024][256]
static constexpr int WB_XPF = 524288;   // f_xproj [144][512]
static constexpr int WB_XPB = 598016;   // b_xproj [144][512]
static constexpr int WB_OWF = 671744;   // f_out_w [256][512]
static constexpr int WB_OWB = 802816;   // b_out_w [256][512]
static constexpr int WB_W2  = 933888;   // w2      [256][256]
static constexpr int WB_DWF = 999424;   // f_dt_w  [512][16]
static constexpr int WB_DWB = 1007616;  // b_dt_w  [512][16]
static constexpr int WB_TOT = 1015808;
// total ws ≈ 39.2 MiB

// ---------------------------------------------------------------------------
// K0: dtype detect (f32 vs bf16).
// ---------------------------------------------------------------------------
__global__ void detect_kernel(const void* __restrict__ x, int* __restrict__ flag) {
  if (threadIdx.x == 0 && blockIdx.x == 0) {
    const u16* p = (const u16*)x;
    int f32 = 0;
    for (int i = 0; i < 512; i += 2) {
      float v = bf2f(p[i]);
      if (!(v > -1024.0f && v < 1024.0f)) f32 = 1;
    }
    *flag = f32;
  }
}

// ---------------------------------------------------------------------------
// K0b: convert all GEMM weights to bf16 into ws (identity if already bf16).
// ---------------------------------------------------------------------------
__global__ __launch_bounds__(256) void convert_kernel(
    const void* __restrict__ f_iw, const void* __restrict__ b_iw,
    const void* __restrict__ f_xp, const void* __restrict__ b_xp,
    const void* __restrict__ f_ow, const void* __restrict__ b_ow,
    const void* __restrict__ w2,   const void* __restrict__ f_dw,
    const void* __restrict__ b_dw, u16* __restrict__ wb,
    const int* __restrict__ flagp) {
  int f32 = *flagp;
  int i = blockIdx.x * 256 + threadIdx.x;
  if (i >= WB_TOT) return;
  const void* src; int off;
  if      (i < WB_IWB) { src = f_iw; off = i - WB_IWF; }
  else if (i < WB_XPF) { src = b_iw; off = i - WB_IWB; }
  else if (i < WB_XPB) { src = f_xp; off = i - WB_XPF; }
  else if (i < WB_OWF) { src = b_xp; off = i - WB_XPB; }
  else if (i < WB_OWB) { src = f_ow; off = i - WB_OWF; }
  else if (i < WB_W2)  { src = b_ow; off = i - WB_OWB; }
  else if (i < WB_DWF) { src = w2;   off = i - WB_W2;  }
  else if (i < WB_DWB) { src = f_dw; off = i - WB_DWF; }
  else                 { src = b_dw; off = i - WB_DWB; }
  wb[i] = f2bf(ldx(src, (size_t)off, f32));
}

// ---------------------------------------------------------------------------
// K1: LayerNorm over d_model=256 (input x -> bf16 ws). 1 block/row.
// ---------------------------------------------------------------------------
__global__ __launch_bounds__(256) void ln1_kernel(
    const void* __restrict__ x, const void* __restrict__ g,
    const void* __restrict__ b, u16* __restrict__ out,
    const int* __restrict__ flagp) {
  int f32 = *flagp;
  int row = blockIdx.x, tid = threadIdx.x;
  float v = ldx(x, (size_t)row * DM + tid, f32);
  float s = v, s2 = v * v;
  for (int o = 32; o; o >>= 1) { s += __shfl_xor(s, o); s2 += __shfl_xor(s2, o); }
  __shared__ float ls[4], ls2[4];
  int wid = tid >> 6;
  if ((tid & 63) == 0) { ls[wid] = s; ls2[wid] = s2; }
  __syncthreads();
  s  = ls[0] + ls[1] + ls[2] + ls[3];
  s2 = ls2[0] + ls2[1] + ls2[2] + ls2[3];
  float mu  = s * (1.0f / DM);
  float var = s2 * (1.0f / DM) - mu * mu;
  float r   = rsqrtf(var + 1e-5f);
  float xn  = (v - mu) * r * ldx(g, tid, f32) + ldx(b, tid, f32);
  out[(size_t)row * DM + tid] = f2bf(xn);
}

// ---------------------------------------------------------------------------
// K2: in-projection (MFMA). xz[dir][m][:] = xn[srow(m)] @ in_w.T  (K=256).
// grid (128, 4, 2), block 256. Wave: 16m x 64n.
// ---------------------------------------------------------------------------
__global__ __launch_bounds__(256) void inproj_kernel(
    const u16* __restrict__ xn, const u16* __restrict__ wb,
    u16* __restrict__ xz) {
  int dir  = blockIdx.z;
  int wave = threadIdx.x >> 6, lane = threadIdx.x & 63;
  int m0 = blockIdx.x * 16;
  int n0 = blockIdx.y * 256 + wave * 64;
  int lm = lane & 15, quad = lane >> 4;
  const short* W = (const short*)(wb + (dir ? WB_IWB : WB_IWF));
  const short* X = (const short*)xn;
  int m = m0 + lm;
  int bb = m >> 10, t = m & 1023;
  int srow = dir ? (bb * 1024 + (1023 - t)) : m;
  f32x4 acc[4] = {};
  for (int k0 = 0; k0 < DM; k0 += 32) {
    bf16x8 a = *(const bf16x8*)(X + (size_t)srow * DM + k0 + quad * 8);
#pragma unroll
    for (int c = 0; c < 4; ++c) {
      bf16x8 bf = *(const bf16x8*)(W + (size_t)(n0 + c * 16 + lm) * DM + k0 + quad * 8);
      acc[c] = MFMA(a, bf, acc[c]);
    }
  }
  u16* out = xz + (size_t)dir * ROWS * NXZ;
#pragma unroll
  for (int c = 0; c < 4; ++c)
#pragma unroll
    for (int r = 0; r < 4; ++r)
      out[(size_t)(m0 + quad * 4 + r) * NXZ + n0 + c * 16 + lm] = f2bf(acc[c][r]);
}

// ---------------------------------------------------------------------------
// K3: depthwise causal conv (width 4) + silu, 8 channels/thread (bf16x8).
// ---------------------------------------------------------------------------
__global__ __launch_bounds__(256) void conv_kernel(
    const u16* __restrict__ xz, const void* __restrict__ f_cw,
    const void* __restrict__ f_cb, const void* __restrict__ b_cw,
    const void* __restrict__ b_cb, u16* __restrict__ xc,
    const int* __restrict__ flagp) {
  int f32 = *flagp;
  int idx = blockIdx.x * 256 + threadIdx.x;   // [0, 2*2048*64)
  int g   = idx & 63;
  int row = (idx >> 6) & (ROWS - 1);
  int dir = idx >> 17;
  int tpos = row & 1023;
  int d0 = g * 8;
  const void* cw = dir ? b_cw : f_cw;
  const void* cb = dir ? b_cb : f_cb;
  const u16* xi = xz + (size_t)dir * ROWS * NXZ;
  float s[8];
#pragma unroll
  for (int e = 0; e < 8; ++e) s[e] = ldx(cb, d0 + e, f32);
#pragma unroll
  for (int k = 0; k < 4; ++k) {
    int tt = tpos - 3 + k;
    if (tt >= 0) {
      bf16x8 xv = *(const bf16x8*)(xi + (size_t)(row + k - 3) * NXZ + d0);
#pragma unroll
      for (int e = 0; e < 8; ++e)
        s[e] += ldx(cw, (d0 + e) * 4 + k, f32) * bf2f((u16)xv[e]);
    }
  }
  bf16x8 ov;
#pragma unroll
  for (int e = 0; e < 8; ++e) {
    float sl = s[e] / (1.0f + __expf(-s[e]));
    ov[e] = (short)f2bf(sl);
  }
  *(bf16x8*)(xc + ((size_t)dir * ROWS + row) * DI + d0) = ov;
}

// ---------------------------------------------------------------------------
// K4: x-projection (MFMA). dbl[m][n] = xc[m] @ xproj_w.T  (K=512), f32 out.
// ---------------------------------------------------------------------------
__global__ __launch_bounds__(256) void xproj_kernel(
    const u16* __restrict__ xc, const u16* __restrict__ wb,
    float* __restrict__ dbl) {
  int wave = threadIdx.x >> 6, lane = threadIdx.x & 63;
  int m0 = blockIdx.x * 64 + wave * 16;          // [0, 4096)
  int n0 = blockIdx.y * 16;
  int lm = lane & 15, quad = lane >> 4;
  const short* W = (const short*)(wb + ((m0 & 2048) ? WB_XPB : WB_XPF));
  const short* X = (const short*)xc;
  f32x4 acc = {};
  for (int k0 = 0; k0 < DI; k0 += 32) {
    bf16x8 a  = *(const bf16x8*)(X + (size_t)(m0 + lm) * DI + k0 + quad * 8);
    bf16x8 bf = *(const bf16x8*)(W + (size_t)(n0 + lm) * DI + k0 + quad * 8);
    acc = MFMA(a, bf, acc);
  }
#pragma unroll
  for (int r = 0; r < 4; ++r)
    dbl[(size_t)(m0 + quad * 4 + r) * NDBL + n0 + lm] = acc[r];
}

// ---------------------------------------------------------------------------
// K5: scan_prep. Blocks 0..127: dt = softplus(dbl[:, :16]@dt_w.T + dt_b),
// write dtT / dxT = dt*xc (bf16, [dirb][d][t]). Blocks 128..191: transpose
// B,C from dbl into BT/CT (f32, [dirb][n][t]).
// ---------------------------------------------------------------------------
__global__ __launch_bounds__(256) void scan_prep(
    const float* __restrict__ dbl, const u16* __restrict__ xc,
    const u16* __restrict__ wb, const void* __restrict__ f_db,
    const void* __restrict__ b_db, u16* __restrict__ dtT,
    u16* __restrict__ dxT, float* __restrict__ BT, float* __restrict__ CT,
    const int* __restrict__ flagp) {
  int f32 = *flagp;
  int blk = blockIdx.x, tid = threadIdx.x;
  if (blk < 128) {
    int dirb = blk >> 5, t0 = (blk & 31) * 32;
    int dir = dirb >> 1;
    __shared__ float dblr[32][16];
    for (int i = tid; i < 512; i += 256)
      dblr[i >> 4][i & 15] =
          dbl[(size_t)(dirb * 1024 + t0 + (i >> 4)) * NDBL + (i & 15)];
    __syncthreads();
    const u16* dwbase = wb + (dir ? WB_DWB : WB_DWF);
    const void* db = dir ? b_db : f_db;
#pragma unroll
    for (int half = 0; half < 2; ++half) {
      int n = tid + half * 256;
      bf16x8 w0 = *(const bf16x8*)(dwbase + n * 16);
      bf16x8 w1 = *(const bf16x8*)(dwbase + n * 16 + 8);
      float bias = ldx(db, n, f32);
      u16 dtl[32], dxl[32];
#pragma unroll
      for (int t = 0; t < 32; ++t) {
        float acc = bias;
#pragma unroll
        for (int k = 0; k < 8; ++k) acc += dblr[t][k] * bf2f((u16)w0[k]);
#pragma unroll
        for (int k = 0; k < 8; ++k) acc += dblr[t][8 + k] * bf2f((u16)w1[k]);
        float sp = (acc > 20.0f) ? acc : log1pf(__expf(acc));
        float xcv = bf2f(xc[(size_t)(dirb * 1024 + t0 + t) * DI + n]);
        dtl[t] = f2bf(sp);
        dxl[t] = f2bf(sp * xcv);
      }
      size_t ob = (size_t)(dirb * 512 + n) * 1024 + t0;
#pragma unroll
      for (int o = 0; o < 4; ++o) {
        bf16x8 v1, v2;
#pragma unroll
        for (int e = 0; e < 8; ++e) {
          v1[e] = (short)dtl[o * 8 + e];
          v2[e] = (short)dxl[o * 8 + e];
        }
        *(bf16x8*)(dtT + ob + o * 8) = v1;
        *(bf16x8*)(dxT + ob + o * 8) = v2;
      }
    }
  } else {
    int u = (blk - 128) * 256 + tid;     // [0, 16384)
    int tg = u & 63, n = (u >> 6) & 63, dirb = u >> 12;
    int t0 = tg * 16;
    float bv[16], cv[16];
#pragma unroll
    for (int i = 0; i < 16; ++i) {
      size_t m = (size_t)(dirb * 1024 + t0 + i) * NDBL;
      bv[i] = dbl[m + 16 + n];
      cv[i] = dbl[m + 80 + n];
    }
    size_t ob = (size_t)(dirb * 64 + n) * 1024 + t0;
#pragma unroll
    for (int i = 0; i < 16; ++i) { BT[ob + i] = bv[i]; CT[ob + i] = cv[i]; }
  }
}

// ---------------------------------------------------------------------------
// K6a: scan pass 1 — (P, b) summaries for chunks 0..6 (128 steps each).
// grid (512, 7), block 256. Wave = (dir,b,d), lane = state.
// ---------------------------------------------------------------------------
__global__ __launch_bounds__(256) void scan_pass1(
    const u16* __restrict__ dtT, const u16* __restrict__ dxT,
    const float* __restrict__ BT,
    const void* __restrict__ f_Al, const void* __restrict__ b_Al,
    float* __restrict__ Pch, float* __restrict__ Bch,
    const int* __restrict__ flagp) {
  int f32 = *flagp;
  int gw = blockIdx.x * 4 + (threadIdx.x >> 6);   // [0, 2048)
  int gwu = __builtin_amdgcn_readfirstlane(gw);
  int c = blockIdx.y;                              // 0..6
  int lane = threadIdx.x & 63;
  int d = gwu & (DI - 1), bb = (gwu >> 9) & 1, dir = gwu >> 10;
  int dirb = dir * 2 + bb;
  float A = -__expf(ldx(dir ? b_Al : f_Al, d * DS + lane, f32));
  size_t tb  = (size_t)(dirb * 512 + d) * 1024;
  size_t btb = (size_t)(dirb * 64 + lane) * 1024;
  float h = 0.0f, P = 1.0f;
  int tbeg = c * 128;
  for (int t0 = tbeg; t0 < tbeg + 128; t0 += 8) {
    bf16x8 dt8 = *(const bf16x8*)(dtT + tb + t0);
    bf16x8 dx8 = *(const bf16x8*)(dxT + tb + t0);
    f32x4 B0 = *(const f32x4*)(BT + btb + t0);
    f32x4 B1 = *(const f32x4*)(BT + btb + t0 + 4);
#pragma unroll
    for (int j = 0; j < 8; ++j) {
      float dtv = bf2f((u16)dt8[j]);
      float dxv = bf2f((u16)dx8[j]);
      float Bv = (j < 4) ? B0[j] : B1[j - 4];
      float dA = __expf(dtv * A);
      h = dA * h + dxv * Bv;
      P *= dA;
    }
  }
  size_t o = ((size_t)gw * 7 + c) * 64 + lane;
  Pch[o] = P;
  Bch[o] = h;
}

// ---------------------------------------------------------------------------
// K6b: scan pass 2 — 8 chunks of 128 in parallel; h_in composed from
// summaries; per-window 5 vector loads + 27-shuffle reduction.
// grid (512, 8), block 256.
// ---------------------------------------------------------------------------
__global__ __launch_bounds__(256) void scan_pass2(
    const u16* __restrict__ dtT, const u16* __restrict__ dxT,
    const float* __restrict__ BT, const float* __restrict__ CT,
    const u16* __restrict__ xc, const u16* __restrict__ xz,
    const void* __restrict__ f_Al, const void* __restrict__ f_Dp,
    const void* __restrict__ b_Al, const void* __restrict__ b_Dp,
    const float* __restrict__ Pch, const float* __restrict__ Bch,
    u16* __restrict__ y, const int* __restrict__ flagp) {
  int f32 = *flagp;
  int gw = blockIdx.x * 4 + (threadIdx.x >> 6);   // [0, 2048)
  int gwu = __builtin_amdgcn_readfirstlane(gw);
  int c = blockIdx.y;                              // 0..7
  int lane = threadIdx.x & 63;
  int grp = lane >> 3;
  int d = gwu & (DI - 1), bb = (gwu >> 9) & 1, dir = gwu >> 10;
  int dirb = dir * 2 + bb;
  float A   = -__expf(ldx(dir ? b_Al : f_Al, d * DS + lane, f32));
  float Dpd = ldx(dir ? b_Dp : f_Dp, d, f32);
  size_t tb  = (size_t)(dirb * 512 + d) * 1024;
  size_t btb = (size_t)(dirb * 64 + lane) * 1024;
  float h = 0.0f;
  for (int cc = 0; cc < c; ++cc) {
    size_t o = ((size_t)gw * 7 + cc) * 64 + lane;
    h = Pch[o] * h + Bch[o];
  }
  int tbeg = c * 128;
  for (int t0 = tbeg; t0 < tbeg + 128; t0 += 8) {
    bf16x8 dt8 = *(const bf16x8*)(dtT + tb + t0);
    bf16x8 dx8 = *(const bf16x8*)(dxT + tb + t0);
    f32x4 B0 = *(const f32x4*)(BT + btb + t0);
    f32x4 B1 = *(const f32x4*)(BT + btb + t0 + 4);
    f32x4 C0 = *(const f32x4*)(CT + btb + t0);
    f32x4 C1 = *(const f32x4*)(CT + btb + t0 + 4);
    float p[8];
#pragma unroll
    for (int j = 0; j < 8; ++j) {
      float dtv = bf2f((u16)dt8[j]);
      float dxv = bf2f((u16)dx8[j]);
      float Bv = (j < 4) ? B0[j] : B1[j - 4];
      float Cv = (j < 4) ? C0[j] : C1[j - 4];
      h = __expf(dtv * A) * h + dxv * Bv;
      p[j] = h * Cv;
    }
    // stage A: residue sums (8 values per j, indexed by lane&7)
#pragma unroll
    for (int j = 0; j < 8; ++j) {
      p[j] += __shfl_xor(p[j], 8);
      p[j] += __shfl_xor(p[j], 16);
      p[j] += __shfl_xor(p[j], 32);
    }
    // register transpose: lane group g carries value index g = lane>>3
    float v = p[0];
#pragma unroll
    for (int j = 1; j < 8; ++j) v = (grp == j) ? p[j] : v;
    // stage B: sum 8 residues within each 8-lane group
    v += __shfl_xor(v, 1);
    v += __shfl_xor(v, 2);
    v += __shfl_xor(v, 4);
    if ((lane & 7) == 0) {
      int t = t0 + grp;
      size_t row = (size_t)(dirb * 1024 + t);
      float xcv = bf2f(xc[row * DI + d]);
      float zv  = bf2f(xz[row * NXZ + DI + d]);
      float yv = (v + xcv * Dpd) * (zv / (1.0f + __expf(-zv)));
      y[row * DI + d] = f2bf(yv);
    }
  }
}

// ---------------------------------------------------------------------------
// K7: out-projection (MFMA, both dirs) + fused LayerNorm2 -> x2 (bf16).
// grid 128, block 256 (4 waves along n). Block owns 16 complete rows.
// ---------------------------------------------------------------------------
__global__ __launch_bounds__(256) void outproj_ln2_kernel(
    const u16* __restrict__ y, const u16* __restrict__ wb,
    const void* __restrict__ g, const void* __restrict__ bta,
    u16* __restrict__ x2, const int* __restrict__ flagp) {
  int f32 = *flagp;
  int wave = threadIdx.x >> 6, lane = threadIdx.x & 63;
  int m0 = blockIdx.x * 16;
  int n0 = wave * 64;
  int lm = lane & 15, quad = lane >> 4;
  const short* Y = (const short*)y;
  int m  = m0 + lm;
  int bb = m >> 10, t = m & 1023;
  int srow_b = ROWS + bb * 1024 + (1023 - t);
  f32x4 acc[4] = {};
  {
    const short* W = (const short*)(wb + WB_OWF);
    for (int k0 = 0; k0 < DI; k0 += 32) {
      bf16x8 a = *(const bf16x8*)(Y + (size_t)m * DI + k0 + quad * 8);
#pragma unroll
      for (int c = 0; c < 4; ++c) {
        bf16x8 bf = *(const bf16x8*)(W + (size_t)(n0 + c * 16 + lm) * DI + k0 + quad * 8);
        acc[c] = MFMA(a, bf, acc[c]);
      }
    }
  }
  {
    const short* W = (const short*)(wb + WB_OWB);
    for (int k0 = 0; k0 < DI; k0 += 32) {
      bf16x8 a = *(const bf16x8*)(Y + (size_t)srow_b * DI + k0 + quad * 8);
#pragma unroll
      for (int c = 0; c < 4; ++c) {
        bf16x8 bf = *(const bf16x8*)(W + (size_t)(n0 + c * 16 + lm) * DI + k0 + quad * 8);
        acc[c] = MFMA(a, bf, acc[c]);
      }
    }
  }
  // ---- fused LN2 over the 256 columns of each of the block's 16 rows ----
  float ps[4], pq[4];
#pragma unroll
  for (int r = 0; r < 4; ++r) {
    ps[r] = acc[0][r] + acc[1][r] + acc[2][r] + acc[3][r];
    pq[r] = acc[0][r] * acc[0][r] + acc[1][r] * acc[1][r] +
            acc[2][r] * acc[2][r] + acc[3][r] * acc[3][r];
  }
#pragma unroll
  for (int off = 1; off < 16; off <<= 1)
#pragma unroll
    for (int r = 0; r < 4; ++r) {
      ps[r] += __shfl_xor(ps[r], off);
      pq[r] += __shfl_xor(pq[r], off);
    }
  __shared__ float S1[16][4], S2[16][4];
  if (lm == 0)
#pragma unroll
    for (int r = 0; r < 4; ++r) {
      S1[quad * 4 + r][wave] = ps[r];
      S2[quad * 4 + r][wave] = pq[r];
    }
  __syncthreads();
  float mu[4], rs[4];
#pragma unroll
  for (int r = 0; r < 4; ++r) {
    int row = quad * 4 + r;
    float s1 = S1[row][0] + S1[row][1] + S1[row][2] + S1[row][3];
    float s2 = S2[row][0] + S2[row][1] + S2[row][2] + S2[row][3];
    float m_ = s1 * (1.0f / DM);
    float v_ = s2 * (1.0f / DM) - m_ * m_;
    mu[r] = m_;
    rs[r] = rsqrtf(v_ + 1e-5f);
  }
#pragma unroll
  for (int c = 0; c < 4; ++c)
#pragma unroll
    for (int r = 0; r < 4; ++r) {
      int col = n0 + c * 16 + lm;
      int row = m0 + quad * 4 + r;
      float val = (acc[c][r] - mu[r]) * rs[r] * ldx(g, col, f32) + ldx(bta, col, f32);
      x2[(size_t)row * DM + col] = f2bf(val);
    }
}

// ---------------------------------------------------------------------------
// K9: out = gelu_exact(x2 @ w2.T + b2) (MFMA). grid 128, block 256.
// ---------------------------------------------------------------------------
__global__ __launch_bounds__(256) void final_kernel(
    const u16* __restrict__ x2, const u16* __restrict__ wb,
    const void* __restrict__ b2, void* __restrict__ out,
    const int* __restrict__ flagp) {
  int f32 = *flagp;
  int wave = threadIdx.x >> 6, lane = threadIdx.x & 63;
  int m0 = blockIdx.x * 16;
  int n0 = wave * 64;
  int lm = lane & 15, quad = lane >> 4;
  const short* X = (const short*)x2;
  const short* W = (const short*)(wb + WB_W2);
  f32x4 acc[4] = {};
  for (int k0 = 0; k0 < DM; k0 += 32) {
    bf16x8 a = *(const bf16x8*)(X + (size_t)(m0 + lm) * DM + k0 + quad * 8);
#pragma unroll
    for (int c = 0; c < 4; ++c) {
      bf16x8 bf = *(const bf16x8*)(W + (size_t)(n0 + c * 16 + lm) * DM + k0 + quad * 8);
      acc[c] = MFMA(a, bf, acc[c]);
    }
  }
#pragma unroll
  for (int c = 0; c < 4; ++c)
#pragma unroll
    for (int r = 0; r < 4; ++r) {
      int col = n0 + c * 16 + lm;
      float v = acc[c][r] + ldx(b2, col, f32);
      float g = 0.5f * v * (1.0f + erff(v * 0.70710678118654752f));
      size_t o = (size_t)(m0 + quad * 4 + r) * DM + col;
      if (f32) ((float*)out)[o] = g;
      else     ((u16*)out)[o]   = f2bf(g);
    }
}

// ---------------------------------------------------------------------------
extern "C" void kernel_launch(void* const* d_in, const int* in_sizes, int n_in,
                              void* d_out, int out_size, void* d_ws, size_t ws_size,
                              hipStream_t stream) {
  const void* x        = d_in[0];
  const void* f_in_w   = d_in[1];
  const void* f_conv_w = d_in[2];
  const void* f_conv_b = d_in[3];
  const void* f_xproj  = d_in[4];
  const void* f_dt_w   = d_in[5];
  const void* f_dt_b   = d_in[6];
  const void* f_A_log  = d_in[7];
  const void* f_Dp     = d_in[8];
  const void* f_out_w  = d_in[9];
  const void* b_in_w   = d_in[10];
  const void* b_conv_w = d_in[11];
  const void* b_conv_b = d_in[12];
  const void* b_xproj  = d_in[13];
  const void* b_dt_w   = d_in[14];
  const void* b_dt_b   = d_in[15];
  const void* b_A_log  = d_in[16];
  const void* b_Dp     = d_in[17];
  const void* b_out_w  = d_in[18];
  const void* ln1_g    = d_in[19];
  const void* ln1_b    = d_in[20];
  const void* ln2_g    = d_in[21];
  const void* ln2_b    = d_in[22];
  const void* w2       = d_in[23];
  const void* b2       = d_in[24];

  char* ws = (char*)d_ws;
  u16*   xn   = (u16*)(ws + XN_OFF);
  u16*   xz   = (u16*)(ws + XZ_OFF);
  u16*   xc   = (u16*)(ws + XC_OFF);
  float* dbl  = (float*)(ws + DBL_OFF);
  u16*   dtT  = (u16*)(ws + DTT_OFF);
  u16*   dxT  = (u16*)(ws + DXT_OFF);
  float* BT   = (float*)(ws + BT_OFF);
  float* CT   = (float*)(ws + CT_OFF);
  u16*   y    = (u16*)(ws + Y_OFF);
  u16*   x2   = (u16*)(ws + X2_OFF);
  float* Pch  = (float*)(ws + PCH_OFF);
  float* Bch  = (float*)(ws + BCH_OFF);
  int*   flag = (int*)(ws + FLAG_OFF);
  u16*   wb   = (u16*)(ws + WB_OFF);

  detect_kernel<<<1, 64, 0, stream>>>(x, flag);
  convert_kernel<<<(WB_TOT + 255) / 256, 256, 0, stream>>>(
      f_in_w, b_in_w, f_xproj, b_xproj, f_out_w, b_out_w, w2, f_dt_w, b_dt_w,
      wb, flag);
  ln1_kernel<<<ROWS, 256, 0, stream>>>(x, ln1_g, ln1_b, xn, flag);
  inproj_kernel<<<dim3(ROWS / 16, 4, 2), 256, 0, stream>>>(xn, wb, xz);
  conv_kernel<<<(2 * ROWS * 64) / 256, 256, 0, stream>>>(
      xz, f_conv_w, f_conv_b, b_conv_w, b_conv_b, xc, flag);
  xproj_kernel<<<dim3(64, 9), 256, 0, stream>>>(xc, wb, dbl);
  scan_prep<<<192, 256, 0, stream>>>(
      dbl, xc, wb, f_dt_b, b_dt_b, dtT, dxT, BT, CT, flag);
  scan_pass1<<<dim3(512, 7), 256, 0, stream>>>(
      dtT, dxT, BT, f_A_log, b_A_log, Pch, Bch, flag);
  scan_pass2<<<dim3(512, 8), 256, 0, stream>>>(
      dtT, dxT, BT, CT, xc, xz, f_A_log, f_Dp, b_A_log, b_Dp, Pch, Bch, y, flag);
  outproj_ln2_kernel<<<ROWS / 16, 256, 0, stream>>>(y, wb, ln2_g, ln2_b, x2, flag);
  final_kernel<<<ROWS / 16, 256, 0, stream>>>(x2, wb, b2, d_out, flag);
}

// Round 8
// 335.594 us; speedup vs baseline: 1.5537x; 1.5537x over previous
//
#include <hip/hip_runtime.h>

// ---------------------------------------------------------------------------
// BiMambaEncoderBlock on MI355X (gfx950). fp32 accumulate, bf16 intermediates.
// B=2, S=1024, D_MODEL=256, D_INNER=512, D_STATE=64, DT_RANK=16, D_CONV=4.
// Round 8: revert B/C to lane-coalesced dbl reads (round-7's [n][t] transpose
// was a 64-way gather -> mem-latency-bound regression). Keep dtT/dxT
// broadcast precompute, 8 chunks of 128, fused LN2. scan_prep 512 blocks.
// ---------------------------------------------------------------------------

typedef unsigned short u16;
typedef short bf16x8 __attribute__((ext_vector_type(8)));   // 8 bf16 = 4 VGPRs
typedef float f32x4  __attribute__((ext_vector_type(4)));

#define MFMA(a, b, c) __builtin_amdgcn_mfma_f32_16x16x32_bf16((a), (b), (c), 0, 0, 0)

static constexpr int ROWS = 2048;   // B*S
static constexpr int DM   = 256;    // d_model
static constexpr int DI   = 512;    // d_inner
static constexpr int NXZ  = 1024;   // 2*d_inner
static constexpr int NDBL = 144;    // dt_rank + 2*d_state
static constexpr int DS   = 64;     // d_state

__device__ __forceinline__ float bf2f(u16 u) {
  union { unsigned u32; float f; } v; v.u32 = ((unsigned)u) << 16; return v.f;
}
__device__ __forceinline__ u16 f2bf(float f) {
  union { float f; unsigned u; } v; v.f = f;
  unsigned r = v.u + 0x7FFFu + ((v.u >> 16) & 1u);   // RNE (finite inputs)
  return (u16)(r >> 16);
}
__device__ __forceinline__ float ldx(const void* p, size_t i, int f32) {
  return f32 ? ((const float*)p)[i] : bf2f(((const u16*)p)[i]);
}

// ---- workspace layout (bytes) ----
static constexpr size_t XN_OFF   = 0;          // bf16 [2048][256]
static constexpr size_t XZ_OFF   = 1048576;    // bf16 [2][2048][1024]
static constexpr size_t XC_OFF   = 9437184;    // bf16 [2][2048][512]  (row=dirb*1024+t)
static constexpr size_t DBL_OFF  = 13631488;   // f32  [4096][144]
static constexpr size_t DTT_OFF  = 15990784;   // bf16 [4][512][1024]  dt  (dirb,d,t)
static constexpr size_t DXT_OFF  = 20185088;   // bf16 [4][512][1024]  dt*xc
static constexpr size_t Y_OFF    = 24379392;   // bf16 [4096][512]
static constexpr size_t X2_OFF   = 28573696;   // bf16 [2048][256]
static constexpr size_t PCH_OFF  = 29622272;   // f32  [2048][7][64]
static constexpr size_t BCH_OFF  = 33292288;   // f32  [2048][7][64]
static constexpr size_t FLAG_OFF = 36962304;   // int
static constexpr size_t WB_OFF   = 36962320;   // bf16 weights
// converted-weight region (element offsets within WB):
static constexpr int WB_IWF = 0;        // f_in_w  [1024][256]
static constexpr int WB_IWB = 262144;   // b_in_w  [1024][256]
static constexpr int WB_XPF = 524288;   // f_xproj [144][512]
static constexpr int WB_XPB = 598016;   // b_xproj [144][512]
static constexpr int WB_OWF = 671744;   // f_out_w [256][512]
static constexpr int WB_OWB = 802816;   // b_out_w [256][512]
static constexpr int WB_W2  = 933888;   // w2      [256][256]
static constexpr int WB_DWF = 999424;   // f_dt_w  [512][16]
static constexpr int WB_DWB = 1007616;  // b_dt_w  [512][16]
static constexpr int WB_TOT = 1015808;
// total ws ≈ 37.2 MiB

// ---------------------------------------------------------------------------
// K0: dtype detect (f32 vs bf16).
// ---------------------------------------------------------------------------
__global__ void detect_kernel(const void* __restrict__ x, int* __restrict__ flag) {
  if (threadIdx.x == 0 && blockIdx.x == 0) {
    const u16* p = (const u16*)x;
    int f32 = 0;
    for (int i = 0; i < 512; i += 2) {
      float v = bf2f(p[i]);
      if (!(v > -1024.0f && v < 1024.0f)) f32 = 1;
    }
    *flag = f32;
  }
}

// ---------------------------------------------------------------------------
// K0b: convert all GEMM weights to bf16 into ws (identity if already bf16).
// ---------------------------------------------------------------------------
__global__ __launch_bounds__(256) void convert_kernel(
    const void* __restrict__ f_iw, const void* __restrict__ b_iw,
    const void* __restrict__ f_xp, const void* __restrict__ b_xp,
    const void* __restrict__ f_ow, const void* __restrict__ b_ow,
    const void* __restrict__ w2,   const void* __restrict__ f_dw,
    const void* __restrict__ b_dw, u16* __restrict__ wb,
    const int* __restrict__ flagp) {
  int f32 = *flagp;
  int i = blockIdx.x * 256 + threadIdx.x;
  if (i >= WB_TOT) return;
  const void* src; int off;
  if      (i < WB_IWB) { src = f_iw; off = i - WB_IWF; }
  else if (i < WB_XPF) { src = b_iw; off = i - WB_IWB; }
  else if (i < WB_XPB) { src = f_xp; off = i - WB_XPF; }
  else if (i < WB_OWF) { src = b_xp; off = i - WB_XPB; }
  else if (i < WB_OWB) { src = f_ow; off = i - WB_OWF; }
  else if (i < WB_W2)  { src = b_ow; off = i - WB_OWB; }
  else if (i < WB_DWF) { src = w2;   off = i - WB_W2;  }
  else if (i < WB_DWB) { src = f_dw; off = i - WB_DWF; }
  else                 { src = b_dw; off = i - WB_DWB; }
  wb[i] = f2bf(ldx(src, (size_t)off, f32));
}

// ---------------------------------------------------------------------------
// K1: LayerNorm over d_model=256 (input x -> bf16 ws). 1 block/row.
// ---------------------------------------------------------------------------
__global__ __launch_bounds__(256) void ln1_kernel(
    const void* __restrict__ x, const void* __restrict__ g,
    const void* __restrict__ b, u16* __restrict__ out,
    const int* __restrict__ flagp) {
  int f32 = *flagp;
  int row = blockIdx.x, tid = threadIdx.x;
  float v = ldx(x, (size_t)row * DM + tid, f32);
  float s = v, s2 = v * v;
  for (int o = 32; o; o >>= 1) { s += __shfl_xor(s, o); s2 += __shfl_xor(s2, o); }
  __shared__ float ls[4], ls2[4];
  int wid = tid >> 6;
  if ((tid & 63) == 0) { ls[wid] = s; ls2[wid] = s2; }
  __syncthreads();
  s  = ls[0] + ls[1] + ls[2] + ls[3];
  s2 = ls2[0] + ls2[1] + ls2[2] + ls2[3];
  float mu  = s * (1.0f / DM);
  float var = s2 * (1.0f / DM) - mu * mu;
  float r   = rsqrtf(var + 1e-5f);
  float xn  = (v - mu) * r * ldx(g, tid, f32) + ldx(b, tid, f32);
  out[(size_t)row * DM + tid] = f2bf(xn);
}

// ---------------------------------------------------------------------------
// K2: in-projection (MFMA). xz[dir][m][:] = xn[srow(m)] @ in_w.T  (K=256).
// grid (128, 4, 2), block 256. Wave: 16m x 64n.
// ---------------------------------------------------------------------------
__global__ __launch_bounds__(256) void inproj_kernel(
    const u16* __restrict__ xn, const u16* __restrict__ wb,
    u16* __restrict__ xz) {
  int dir  = blockIdx.z;
  int wave = threadIdx.x >> 6, lane = threadIdx.x & 63;
  int m0 = blockIdx.x * 16;
  int n0 = blockIdx.y * 256 + wave * 64;
  int lm = lane & 15, quad = lane >> 4;
  const short* W = (const short*)(wb + (dir ? WB_IWB : WB_IWF));
  const short* X = (const short*)xn;
  int m = m0 + lm;
  int bb = m >> 10, t = m & 1023;
  int srow = dir ? (bb * 1024 + (1023 - t)) : m;
  f32x4 acc[4] = {};
  for (int k0 = 0; k0 < DM; k0 += 32) {
    bf16x8 a = *(const bf16x8*)(X + (size_t)srow * DM + k0 + quad * 8);
#pragma unroll
    for (int c = 0; c < 4; ++c) {
      bf16x8 bf = *(const bf16x8*)(W + (size_t)(n0 + c * 16 + lm) * DM + k0 + quad * 8);
      acc[c] = MFMA(a, bf, acc[c]);
    }
  }
  u16* out = xz + (size_t)dir * ROWS * NXZ;
#pragma unroll
  for (int c = 0; c < 4; ++c)
#pragma unroll
    for (int r = 0; r < 4; ++r)
      out[(size_t)(m0 + quad * 4 + r) * NXZ + n0 + c * 16 + lm] = f2bf(acc[c][r]);
}

// ---------------------------------------------------------------------------
// K3: depthwise causal conv (width 4) + silu, 8 channels/thread (bf16x8).
// ---------------------------------------------------------------------------
__global__ __launch_bounds__(256) void conv_kernel(
    const u16* __restrict__ xz, const void* __restrict__ f_cw,
    const void* __restrict__ f_cb, const void* __restrict__ b_cw,
    const void* __restrict__ b_cb, u16* __restrict__ xc,
    const int* __restrict__ flagp) {
  int f32 = *flagp;
  int idx = blockIdx.x * 256 + threadIdx.x;   // [0, 2*2048*64)
  int g   = idx & 63;
  int row = (idx >> 6) & (ROWS - 1);
  int dir = idx >> 17;
  int tpos = row & 1023;
  int d0 = g * 8;
  const void* cw = dir ? b_cw : f_cw;
  const void* cb = dir ? b_cb : f_cb;
  const u16* xi = xz + (size_t)dir * ROWS * NXZ;
  float s[8];
#pragma unroll
  for (int e = 0; e < 8; ++e) s[e] = ldx(cb, d0 + e, f32);
#pragma unroll
  for (int k = 0; k < 4; ++k) {
    int tt = tpos - 3 + k;
    if (tt >= 0) {
      bf16x8 xv = *(const bf16x8*)(xi + (size_t)(row + k - 3) * NXZ + d0);
#pragma unroll
      for (int e = 0; e < 8; ++e)
        s[e] += ldx(cw, (d0 + e) * 4 + k, f32) * bf2f((u16)xv[e]);
    }
  }
  bf16x8 ov;
#pragma unroll
  for (int e = 0; e < 8; ++e) {
    float sl = s[e] / (1.0f + __expf(-s[e]));
    ov[e] = (short)f2bf(sl);
  }
  *(bf16x8*)(xc + ((size_t)dir * ROWS + row) * DI + d0) = ov;
}

// ---------------------------------------------------------------------------
// K4: x-projection (MFMA). dbl[m][n] = xc[m] @ xproj_w.T  (K=512), f32 out.
// ---------------------------------------------------------------------------
__global__ __launch_bounds__(256) void xproj_kernel(
    const u16* __restrict__ xc, const u16* __restrict__ wb,
    float* __restrict__ dbl) {
  int wave = threadIdx.x >> 6, lane = threadIdx.x & 63;
  int m0 = blockIdx.x * 64 + wave * 16;          // [0, 4096)
  int n0 = blockIdx.y * 16;
  int lm = lane & 15, quad = lane >> 4;
  const short* W = (const short*)(wb + ((m0 & 2048) ? WB_XPB : WB_XPF));
  const short* X = (const short*)xc;
  f32x4 acc = {};
  for (int k0 = 0; k0 < DI; k0 += 32) {
    bf16x8 a  = *(const bf16x8*)(X + (size_t)(m0 + lm) * DI + k0 + quad * 8);
    bf16x8 bf = *(const bf16x8*)(W + (size_t)(n0 + lm) * DI + k0 + quad * 8);
    acc = MFMA(a, bf, acc);
  }
#pragma unroll
  for (int r = 0; r < 4; ++r)
    dbl[(size_t)(m0 + quad * 4 + r) * NDBL + n0 + lm] = acc[r];
}

// ---------------------------------------------------------------------------
// K5: scan_prep. dt = softplus(dbl[:, :16]@dt_w.T + dt_b); write transposed
// dtT / dxT = dt*xc (bf16, [dirb][d][t]). grid 512 (dirb x 128 t-tiles of 8),
// block 256 (each thread covers n and n+256).
// ---------------------------------------------------------------------------
__global__ __launch_bounds__(256) void scan_prep(
    const float* __restrict__ dbl, const u16* __restrict__ xc,
    const u16* __restrict__ wb, const void* __restrict__ f_db,
    const void* __restrict__ b_db, u16* __restrict__ dtT,
    u16* __restrict__ dxT, const int* __restrict__ flagp) {
  int f32 = *flagp;
  int blk = blockIdx.x, tid = threadIdx.x;
  int dirb = blk >> 7, t0 = (blk & 127) * 8;
  int dir = dirb >> 1;
  __shared__ float dblr[8][16];
  if (tid < 128)
    dblr[tid >> 4][tid & 15] =
        dbl[(size_t)(dirb * 1024 + t0 + (tid >> 4)) * NDBL + (tid & 15)];
  __syncthreads();
  const u16* dwbase = wb + (dir ? WB_DWB : WB_DWF);
  const void* db = dir ? b_db : f_db;
#pragma unroll
  for (int half = 0; half < 2; ++half) {
    int n = tid + half * 256;
    bf16x8 w0 = *(const bf16x8*)(dwbase + n * 16);
    bf16x8 w1 = *(const bf16x8*)(dwbase + n * 16 + 8);
    float bias = ldx(db, n, f32);
    bf16x8 v1, v2;
#pragma unroll
    for (int t = 0; t < 8; ++t) {
      float acc = bias;
#pragma unroll
      for (int k = 0; k < 8; ++k) acc += dblr[t][k] * bf2f((u16)w0[k]);
#pragma unroll
      for (int k = 0; k < 8; ++k) acc += dblr[t][8 + k] * bf2f((u16)w1[k]);
      float sp = (acc > 20.0f) ? acc : log1pf(__expf(acc));
      float xcv = bf2f(xc[(size_t)(dirb * 1024 + t0 + t) * DI + n]);
      v1[t] = (short)f2bf(sp);
      v2[t] = (short)f2bf(sp * xcv);
    }
    size_t ob = (size_t)(dirb * 512 + n) * 1024 + t0;
    *(bf16x8*)(dtT + ob) = v1;
    *(bf16x8*)(dxT + ob) = v2;
  }
}

// ---------------------------------------------------------------------------
// K6a: scan pass 1 — (P, b) summaries for chunks 0..6 (128 steps each).
// grid (512, 7), block 256. Wave = (dir,b,d), lane = state.
// B is lane-coalesced straight from dbl; dt/dx are wave-uniform broadcasts.
// ---------------------------------------------------------------------------
__global__ __launch_bounds__(256) void scan_pass1(
    const u16* __restrict__ dtT, const u16* __restrict__ dxT,
    const float* __restrict__ dbl,
    const void* __restrict__ f_Al, const void* __restrict__ b_Al,
    float* __restrict__ Pch, float* __restrict__ Bch,
    const int* __restrict__ flagp) {
  int f32 = *flagp;
  int gw = blockIdx.x * 4 + (threadIdx.x >> 6);   // [0, 2048)
  int gwu = __builtin_amdgcn_readfirstlane(gw);
  int c = blockIdx.y;                              // 0..6
  int lane = threadIdx.x & 63;
  int d = gwu & (DI - 1), bb = (gwu >> 9) & 1, dir = gwu >> 10;
  int dirb = dir * 2 + bb;
  float A = -__expf(ldx(dir ? b_Al : f_Al, d * DS + lane, f32));
  size_t tb  = (size_t)(dirb * 512 + d) * 1024;
  size_t dblbase = (size_t)(dirb * 1024) * NDBL;
  float h = 0.0f, P = 1.0f;
  int tbeg = c * 128;
  for (int t0 = tbeg; t0 < tbeg + 128; t0 += 8) {
    bf16x8 dt8 = *(const bf16x8*)(dtT + tb + t0);
    bf16x8 dx8 = *(const bf16x8*)(dxT + tb + t0);
    float Bv[8];
#pragma unroll
    for (int j = 0; j < 8; ++j)
      Bv[j] = dbl[dblbase + (size_t)(t0 + j) * NDBL + 16 + lane];
#pragma unroll
    for (int j = 0; j < 8; ++j) {
      float dtv = bf2f((u16)dt8[j]);
      float dxv = bf2f((u16)dx8[j]);
      float dA = __expf(dtv * A);
      h = dA * h + dxv * Bv[j];
      P *= dA;
    }
  }
  size_t o = ((size_t)gw * 7 + c) * 64 + lane;
  Pch[o] = P;
  Bch[o] = h;
}

// ---------------------------------------------------------------------------
// K6b: scan pass 2 — 8 chunks of 128 in parallel; h_in composed from
// summaries; lane-coalesced B/C + broadcast dt/dx; 27-shuffle reduction.
// grid (512, 8), block 256.
// ---------------------------------------------------------------------------
__global__ __launch_bounds__(256) void scan_pass2(
    const u16* __restrict__ dtT, const u16* __restrict__ dxT,
    const float* __restrict__ dbl,
    const u16* __restrict__ xc, const u16* __restrict__ xz,
    const void* __restrict__ f_Al, const void* __restrict__ f_Dp,
    const void* __restrict__ b_Al, const void* __restrict__ b_Dp,
    const float* __restrict__ Pch, const float* __restrict__ Bch,
    u16* __restrict__ y, const int* __restrict__ flagp) {
  int f32 = *flagp;
  int gw = blockIdx.x * 4 + (threadIdx.x >> 6);   // [0, 2048)
  int gwu = __builtin_amdgcn_readfirstlane(gw);
  int c = blockIdx.y;                              // 0..7
  int lane = threadIdx.x & 63;
  int grp = lane >> 3;
  int d = gwu & (DI - 1), bb = (gwu >> 9) & 1, dir = gwu >> 10;
  int dirb = dir * 2 + bb;
  float A   = -__expf(ldx(dir ? b_Al : f_Al, d * DS + lane, f32));
  float Dpd = ldx(dir ? b_Dp : f_Dp, d, f32);
  size_t tb  = (size_t)(dirb * 512 + d) * 1024;
  size_t dblbase = (size_t)(dirb * 1024) * NDBL;
  float h = 0.0f;
  for (int cc = 0; cc < c; ++cc) {
    size_t o = ((size_t)gw * 7 + cc) * 64 + lane;
    h = Pch[o] * h + Bch[o];
  }
  int tbeg = c * 128;
  for (int t0 = tbeg; t0 < tbeg + 128; t0 += 8) {
    bf16x8 dt8 = *(const bf16x8*)(dtT + tb + t0);
    bf16x8 dx8 = *(const bf16x8*)(dxT + tb + t0);
    float Bv[8], Cv[8], p[8];
#pragma unroll
    for (int j = 0; j < 8; ++j) {
      size_t m = dblbase + (size_t)(t0 + j) * NDBL;
      Bv[j] = dbl[m + 16 + lane];
      Cv[j] = dbl[m + 80 + lane];
    }
#pragma unroll
    for (int j = 0; j < 8; ++j) {
      float dtv = bf2f((u16)dt8[j]);
      float dxv = bf2f((u16)dx8[j]);
      h = __expf(dtv * A) * h + dxv * Bv[j];
      p[j] = h * Cv[j];
    }
    // stage A: residue sums (8 values per j, indexed by lane&7)
#pragma unroll
    for (int j = 0; j < 8; ++j) {
      p[j] += __shfl_xor(p[j], 8);
      p[j] += __shfl_xor(p[j], 16);
      p[j] += __shfl_xor(p[j], 32);
    }
    // register transpose: lane group g carries value index g = lane>>3
    float v = p[0];
#pragma unroll
    for (int j = 1; j < 8; ++j) v = (grp == j) ? p[j] : v;
    // stage B: sum 8 residues within each 8-lane group
    v += __shfl_xor(v, 1);
    v += __shfl_xor(v, 2);
    v += __shfl_xor(v, 4);
    if ((lane & 7) == 0) {
      int t = t0 + grp;
      size_t row = (size_t)(dirb * 1024 + t);
      float xcv = bf2f(xc[row * DI + d]);
      float zv  = bf2f(xz[row * NXZ + DI + d]);
      float yv = (v + xcv * Dpd) * (zv / (1.0f + __expf(-zv)));
      y[row * DI + d] = f2bf(yv);
    }
  }
}

// ---------------------------------------------------------------------------
// K7: out-projection (MFMA, both dirs) + fused LayerNorm2 -> x2 (bf16).
// grid 128, block 256 (4 waves along n). Block owns 16 complete rows.
// ---------------------------------------------------------------------------
__global__ __launch_bounds__(256) void outproj_ln2_kernel(
    const u16* __restrict__ y, const u16* __restrict__ wb,
    const void* __restrict__ g, const void* __restrict__ bta,
    u16* __restrict__ x2, const int* __restrict__ flagp) {
  int f32 = *flagp;
  int wave = threadIdx.x >> 6, lane = threadIdx.x & 63;
  int m0 = blockIdx.x * 16;
  int n0 = wave * 64;
  int lm = lane & 15, quad = lane >> 4;
  const short* Y = (const short*)y;
  int m  = m0 + lm;
  int bb = m >> 10, t = m & 1023;
  int srow_b = ROWS + bb * 1024 + (1023 - t);
  f32x4 acc[4] = {};
  {
    const short* W = (const short*)(wb + WB_OWF);
    for (int k0 = 0; k0 < DI; k0 += 32) {
      bf16x8 a = *(const bf16x8*)(Y + (size_t)m * DI + k0 + quad * 8);
#pragma unroll
      for (int c = 0; c < 4; ++c) {
        bf16x8 bf = *(const bf16x8*)(W + (size_t)(n0 + c * 16 + lm) * DI + k0 + quad * 8);
        acc[c] = MFMA(a, bf, acc[c]);
      }
    }
  }
  {
    const short* W = (const short*)(wb + WB_OWB);
    for (int k0 = 0; k0 < DI; k0 += 32) {
      bf16x8 a = *(const bf16x8*)(Y + (size_t)srow_b * DI + k0 + quad * 8);
#pragma unroll
      for (int c = 0; c < 4; ++c) {
        bf16x8 bf = *(const bf16x8*)(W + (size_t)(n0 + c * 16 + lm) * DI + k0 + quad * 8);
        acc[c] = MFMA(a, bf, acc[c]);
      }
    }
  }
  // ---- fused LN2 over the 256 columns of each of the block's 16 rows ----
  float ps[4], pq[4];
#pragma unroll
  for (int r = 0; r < 4; ++r) {
    ps[r] = acc[0][r] + acc[1][r] + acc[2][r] + acc[3][r];
    pq[r] = acc[0][r] * acc[0][r] + acc[1][r] * acc[1][r] +
            acc[2][r] * acc[2][r] + acc[3][r] * acc[3][r];
  }
#pragma unroll
  for (int off = 1; off < 16; off <<= 1)
#pragma unroll
    for (int r = 0; r < 4; ++r) {
      ps[r] += __shfl_xor(ps[r], off);
      pq[r] += __shfl_xor(pq[r], off);
    }
  __shared__ float S1[16][4], S2[16][4];
  if (lm == 0)
#pragma unroll
    for (int r = 0; r < 4; ++r) {
      S1[quad * 4 + r][wave] = ps[r];
      S2[quad * 4 + r][wave] = pq[r];
    }
  __syncthreads();
  float mu[4], rs[4];
#pragma unroll
  for (int r = 0; r < 4; ++r) {
    int row = quad * 4 + r;
    float s1 = S1[row][0] + S1[row][1] + S1[row][2] + S1[row][3];
    float s2 = S2[row][0] + S2[row][1] + S2[row][2] + S2[row][3];
    float m_ = s1 * (1.0f / DM);
    float v_ = s2 * (1.0f / DM) - m_ * m_;
    mu[r] = m_;
    rs[r] = rsqrtf(v_ + 1e-5f);
  }
#pragma unroll
  for (int c = 0; c < 4; ++c)
#pragma unroll
    for (int r = 0; r < 4; ++r) {
      int col = n0 + c * 16 + lm;
      int row = m0 + quad * 4 + r;
      float val = (acc[c][r] - mu[r]) * rs[r] * ldx(g, col, f32) + ldx(bta, col, f32);
      x2[(size_t)row * DM + col] = f2bf(val);
    }
}

// ---------------------------------------------------------------------------
// K9: out = gelu_exact(x2 @ w2.T + b2) (MFMA). grid 128, block 256.
// ---------------------------------------------------------------------------
__global__ __launch_bounds__(256) void final_kernel(
    const u16* __restrict__ x2, const u16* __restrict__ wb,
    const void* __restrict__ b2, void* __restrict__ out,
    const int* __restrict__ flagp) {
  int f32 = *flagp;
  int wave = threadIdx.x >> 6, lane = threadIdx.x & 63;
  int m0 = blockIdx.x * 16;
  int n0 = wave * 64;
  int lm = lane & 15, quad = lane >> 4;
  const short* X = (const short*)x2;
  const short* W = (const short*)(wb + WB_W2);
  f32x4 acc[4] = {};
  for (int k0 = 0; k0 < DM; k0 += 32) {
    bf16x8 a = *(const bf16x8*)(X + (size_t)(m0 + lm) * DM + k0 + quad * 8);
#pragma unroll
    for (int c = 0; c < 4; ++c) {
      bf16x8 bf = *(const bf16x8*)(W + (size_t)(n0 + c * 16 + lm) * DM + k0 + quad * 8);
      acc[c] = MFMA(a, bf, acc[c]);
    }
  }
#pragma unroll
  for (int c = 0; c < 4; ++c)
#pragma unroll
    for (int r = 0; r < 4; ++r) {
      int col = n0 + c * 16 + lm;
      float v = acc[c][r] + ldx(b2, col, f32);
      float g = 0.5f * v * (1.0f + erff(v * 0.70710678118654752f));
      size_t o = (size_t)(m0 + quad * 4 + r) * DM + col;
      if (f32) ((float*)out)[o] = g;
      else     ((u16*)out)[o]   = f2bf(g);
    }
}

// ---------------------------------------------------------------------------
extern "C" void kernel_launch(void* const* d_in, const int* in_sizes, int n_in,
                              void* d_out, int out_size, void* d_ws, size_t ws_size,
                              hipStream_t stream) {
  const void* x        = d_in[0];
  const void* f_in_w   = d_in[1];
  const void* f_conv_w = d_in[2];
  const void* f_conv_b = d_in[3];
  const void* f_xproj  = d_in[4];
  const void* f_dt_w   = d_in[5];
  const void* f_dt_b   = d_in[6];
  const void* f_A_log  = d_in[7];
  const void* f_Dp     = d_in[8];
  const void* f_out_w  = d_in[9];
  const void* b_in_w   = d_in[10];
  const void* b_conv_w = d_in[11];
  const void* b_conv_b = d_in[12];
  const void* b_xproj  = d_in[13];
  const void* b_dt_w   = d_in[14];
  const void* b_dt_b   = d_in[15];
  const void* b_A_log  = d_in[16];
  const void* b_Dp     = d_in[17];
  const void* b_out_w  = d_in[18];
  const void* ln1_g    = d_in[19];
  const void* ln1_b    = d_in[20];
  const void* ln2_g    = d_in[21];
  const void* ln2_b    = d_in[22];
  const void* w2       = d_in[23];
  const void* b2       = d_in[24];

  char* ws = (char*)d_ws;
  u16*   xn   = (u16*)(ws + XN_OFF);
  u16*   xz   = (u16*)(ws + XZ_OFF);
  u16*   xc   = (u16*)(ws + XC_OFF);
  float* dbl  = (float*)(ws + DBL_OFF);
  u16*   dtT  = (u16*)(ws + DTT_OFF);
  u16*   dxT  = (u16*)(ws + DXT_OFF);
  u16*   y    = (u16*)(ws + Y_OFF);
  u16*   x2   = (u16*)(ws + X2_OFF);
  float* Pch  = (float*)(ws + PCH_OFF);
  float* Bch  = (float*)(ws + BCH_OFF);
  int*   flag = (int*)(ws + FLAG_OFF);
  u16*   wb   = (u16*)(ws + WB_OFF);

  detect_kernel<<<1, 64, 0, stream>>>(x, flag);
  convert_kernel<<<(WB_TOT + 255) / 256, 256, 0, stream>>>(
      f_in_w, b_in_w, f_xproj, b_xproj, f_out_w, b_out_w, w2, f_dt_w, b_dt_w,
      wb, flag);
  ln1_kernel<<<ROWS, 256, 0, stream>>>(x, ln1_g, ln1_b, xn, flag);
  inproj_kernel<<<dim3(ROWS / 16, 4, 2), 256, 0, stream>>>(xn, wb, xz);
  conv_kernel<<<(2 * ROWS * 64) / 256, 256, 0, stream>>>(
      xz, f_conv_w, f_conv_b, b_conv_w, b_conv_b, xc, flag);
  xproj_kernel<<<dim3(64, 9), 256, 0, stream>>>(xc, wb, dbl);
  scan_prep<<<512, 256, 0, stream>>>(
      dbl, xc, wb, f_dt_b, b_dt_b, dtT, dxT, flag);
  scan_pass1<<<dim3(512, 7), 256, 0, stream>>>(
      dtT, dxT, dbl, f_A_log, b_A_log, Pch, Bch, flag);
  scan_pass2<<<dim3(512, 8), 256, 0, stream>>>(
      dtT, dxT, dbl, xc, xz, f_A_log, f_Dp, b_A_log, b_Dp, Pch, Bch, y, flag);
  outproj_ln2_kernel<<<ROWS / 16, 256, 0, stream>>>(y, wb, ln2_g, ln2_b, x2, flag);
  final_kernel<<<ROWS / 16, 256, 0, stream>>>(x2, wb, b2, d_out, flag);
}